// Round 3
// baseline (1281.890 us; speedup 1.0000x reference)
//
#include <hip/hip_runtime.h>
#include <hip/hip_fp16.h>

typedef _Float16 half_t;
typedef _Float16 half2_t __attribute__((ext_vector_type(2)));
typedef _Float16 f16x8 __attribute__((ext_vector_type(8)));
typedef float f32x4 __attribute__((ext_vector_type(4)));
typedef unsigned int u32;

// B=256, T=500, I=H=256, O=128, M=B*T=128000
#define MROWS 128000
#define KDIM 256

// ---------------- prep: convert weights to f16 layouts, fold biases ----------
__global__ __launch_bounds__(256) void prep_kernel(
    const float* __restrict__ Wih0, const float* __restrict__ Whh0,
    const float* __restrict__ bih0, const float* __restrict__ bhh0,
    const float* __restrict__ Wih1, const float* __restrict__ Whh1,
    const float* __restrict__ bih1, const float* __restrict__ bhh1,
    const float* __restrict__ fcW,  const float* __restrict__ fcb,
    half_t* __restrict__ Wh0, half_t* __restrict__ Wh1, half_t* __restrict__ fcWh,
    half_t* __restrict__ Whh0h, half_t* __restrict__ Whh1h,
    float* __restrict__ bias0, float* __restrict__ bias1, float* __restrict__ bias2)
{
    int e = blockIdx.x * 256 + threadIdx.x;   // 0..65535
    Wh0[e] = (half_t)Wih0[e];
    Wh1[e] = (half_t)Wih1[e];
    Whh0h[e] = (half_t)Whh0[e];
    Whh1h[e] = (half_t)Whh1[e];
    if (e < 32768) fcWh[e] = (half_t)fcW[e];
    if (e < 256) { bias0[e] = bih0[e] + bhh0[e]; bias1[e] = bih1[e] + bhh1[e]; }
    if (e < 128) { bias2[e] = fcb[e]; }
}

// ---------------- GEMM: C[M,NT] = A[M,256] * W[NT,256]^T + bias (f16 MFMA) ---
template<typename AT, typename OT, int NT, bool SIG>
__global__ __launch_bounds__(512) void gemm_bt(
    const AT* __restrict__ A, const half_t* __restrict__ W,
    const float* __restrict__ bias, OT* __restrict__ C)
{
    constexpr int K = KDIM;
    __shared__ __align__(16) half_t As[128][72];   // +8 pad: 2-way bank alias only
    __shared__ __align__(16) half_t Ws[NT][72];
    __shared__ float bs[NT];
    const int tid  = threadIdx.x;
    const int row0 = blockIdx.x * 128;
    if (tid < NT) bs[tid] = bias[tid];
    constexpr int NFRAG = NT / 64;                 // 4 (NT=256) or 2 (NT=128)
    f32x4 acc[4][NFRAG] = {};
    const int lane = tid & 63;
    const int wid  = tid >> 6;                     // 8 waves: 2 (rows) x 4 (cols)
    const int wr = wid >> 2, wc = wid & 3;

    for (int kt = 0; kt < 4; ++kt) {
        const int k0 = kt * 64;
        if constexpr (sizeof(AT) == 4) {           // fp32 A -> convert to f16
            #pragma unroll
            for (int p = 0; p < 4; ++p) {
                int idx = p * 512 + tid; int r = idx >> 4; int c4 = (idx & 15) * 4;
                const float4 v = *(const float4*)(A + (size_t)(row0 + r) * K + k0 + c4);
                half2_t h01; h01.x = (half_t)v.x; h01.y = (half_t)v.y;
                half2_t h23; h23.x = (half_t)v.z; h23.y = (half_t)v.w;
                *(half2_t*)&As[r][c4]     = h01;
                *(half2_t*)&As[r][c4 + 2] = h23;
            }
        } else {                                   // f16 A
            #pragma unroll
            for (int p = 0; p < 2; ++p) {
                int idx = p * 512 + tid; int r = idx >> 3; int c8 = (idx & 7) * 8;
                uint4 v = *(const uint4*)(A + (size_t)(row0 + r) * K + k0 + c8);
                *(uint4*)&As[r][c8] = v;
            }
        }
        #pragma unroll
        for (int p = 0; p < NT / 64; ++p) {        // stage W tile (f16)
            int idx = p * 512 + tid; int r = idx >> 3; int c8 = (idx & 7) * 8;
            uint4 v = *(const uint4*)(W + (size_t)r * K + k0 + c8);
            *(uint4*)&Ws[r][c8] = v;
        }
        __syncthreads();
        #pragma unroll
        for (int kkh = 0; kkh < 2; ++kkh) {
            const int kk = kkh * 32 + ((lane >> 4) * 8);
            f16x8 af[4], bf[NFRAG];
            #pragma unroll
            for (int m = 0; m < 4; ++m)
                af[m] = *(const f16x8*)&As[wr * 64 + m * 16 + (lane & 15)][kk];
            #pragma unroll
            for (int n = 0; n < NFRAG; ++n)
                bf[n] = *(const f16x8*)&Ws[wc * (NT / 4) + n * 16 + (lane & 15)][kk];
            #pragma unroll
            for (int m = 0; m < 4; ++m)
                #pragma unroll
                for (int n = 0; n < NFRAG; ++n)
                    acc[m][n] = __builtin_amdgcn_mfma_f32_16x16x32_f16(af[m], bf[n], acc[m][n], 0, 0, 0);
        }
        __syncthreads();
    }
    #pragma unroll
    for (int m = 0; m < 4; ++m)
        #pragma unroll
        for (int n = 0; n < NFRAG; ++n)
            #pragma unroll
            for (int jj = 0; jj < 4; ++jj) {
                int rl = wr * 64 + m * 16 + ((lane >> 4) * 4) + jj;
                int cl = wc * (NT / 4) + n * 16 + (lane & 15);
                float v = acc[m][n][jj] + bs[cl];
                if constexpr (SIG) v = 1.0f / (1.0f + __expf(-v));
                C[(size_t)(row0 + rl) * NT + cl] = (OT)v;
            }
}

// ---------------- MFMA recurrent scan ---------------------------------------
// 16 blocks x 256 threads (4 waves). Block owns 16 batch rows.
// Per step: h_new[16b][256j] = tanh(W_hh[j][k] . h[k][b] + xp[b][j])
//   - W_hh: j-quarter per wave, resident in 128 VGPRs (A-operand frags)
//   - h:    double-buffered 8KB LDS tile [b][k], XOR-swizzled, B-operand frags
//   - xp:   prefetched 1 step ahead via global_load_lds (pre-swizzled source)
//   - h out: scattered 8B global stores, layout [b][t][j] (byte-masked HBM)

typedef __attribute__((address_space(1))) const unsigned gu32;
typedef __attribute__((address_space(3))) unsigned lu32;

__device__ __forceinline__ void stage16(const void* g, void* l) {
    __builtin_amdgcn_global_load_lds((gu32*)g, (lu32*)l, 16, 0, 0);
}

__device__ __forceinline__ int swz(int b, int byteoff) {
    return b * 512 + (byteoff ^ ((b & 7) << 4));
}

__device__ __forceinline__ float tanh_fast(float x) {
    // tanh(x) = 1 - 2/(e^{2x}+1);  e^{2x} = exp2(2*log2(e)*x)
    float e = __builtin_amdgcn_exp2f(x * 2.885390082f);
    return __builtin_fmaf(-2.0f, __builtin_amdgcn_rcpf(e + 1.0f), 1.0f);
}

__global__ __launch_bounds__(256, 1) void rnn_scan_mfma(
    const half_t* __restrict__ Whh,   // [256 j][256 k] f16
    const half_t* __restrict__ xp,    // [B*T][256] f16, bias folded
    half_t* __restrict__ hout)        // [B*T][256] f16
{
    __shared__ __align__(16) char lds[32768];
    char* const hs0 = lds;            // h slots: 2 x 8192 B, [16 b][512 B] swizzled
    char* const xs0 = lds + 16384;    // xp slots: 2 x 8192 B, same layout

    const int tid = threadIdx.x;
    const int w = tid >> 6, l = tid & 63, lq = l >> 4, bl = l & 15;
    const int blk = blockIdx.x;

    // resident W_hh fragments: rows j = w*64 + m*16 + bl, k = kt*32 + lq*8 (+0..7)
    f16x8 wf[4][8];
    #pragma unroll
    for (int m = 0; m < 4; ++m)
        #pragma unroll
        for (int kt = 0; kt < 8; ++kt)
            wf[m][kt] = *(const f16x8*)(Whh + (size_t)(w * 64 + m * 16 + bl) * 256 + kt * 32 + lq * 8);

    // zero h slot 0 (h(-1) = 0)
    uint4 z = {0u, 0u, 0u, 0u};
    ((uint4*)hs0)[tid] = z;
    ((uint4*)hs0)[256 + tid] = z;

    // per-lane xp stage sources (pre-swizzled global addresses), at t=0
    const char* srcA; const char* srcB;
    {
        int b0 = tid >> 5,          c0 = (tid & 31) * 16;
        int b1 = (256 + tid) >> 5,  c1 = (tid & 31) * 16;   // (256+tid)&31 == tid&31
        srcA = (const char*)xp + (size_t)(blk * 16 + b0) * 500 * 512 + (c0 ^ ((b0 & 7) << 4));
        srcB = (const char*)xp + (size_t)(blk * 16 + b1) * 500 * 512 + (c1 ^ ((b1 & 7) << 4));
    }
    // stage xp(0) into xp slot 0 (dest: wave-uniform base, HW adds lane*16)
    stage16(srcA, xs0 + w * 1024);
    stage16(srcB, xs0 + 4096 + w * 1024);

    // h global store base: element (blk*16+bl, t, w*64 + m*16 + lq*4 + jj)
    char* hst = (char*)hout + ((size_t)(blk * 16 + bl) * 500 * 256 + w * 64 + lq * 4) * 2;

    __syncthreads();   // h zeros + W loads ordered; stage(0) in flight

    auto step = [&](int t, char* hcur, char* hnxt, const char* xcur, char* xnxt, bool last) {
        // prefetch xp(t+1) into the other xp slot (safe: slot was fully read
        // at step t-1 and all waves crossed the step t-1 barrier already)
        srcA += 512; srcB += 512;
        if (!last) {
            stage16(srcA, xnxt + w * 1024);
            stage16(srcB, xnxt + 4096 + w * 1024);
        }
        // B-operand fragments: h[k = kt*32+lq*8 ..+7][b = bl]
        f16x8 bf[8];
        #pragma unroll
        for (int kt = 0; kt < 8; ++kt)
            bf[kt] = *(const f16x8*)(hcur + swz(bl, kt * 64 + lq * 16));
        f32x4 acc[4] = {};
        #pragma unroll
        for (int kt = 0; kt < 8; ++kt)
            #pragma unroll
            for (int m = 0; m < 4; ++m)
                acc[m] = __builtin_amdgcn_mfma_f32_16x16x32_f16(wf[m][kt], bf[kt], acc[m], 0, 0, 0);
        // wait xp(t) staged (leaves the 2 stage(t+1) loads in flight)
        asm volatile("s_waitcnt vmcnt(2)" ::: "memory");
        __builtin_amdgcn_sched_barrier(0);
        #pragma unroll
        for (int m = 0; m < 4; ++m) {
            const int off = w * 128 + m * 32 + lq * 8;
            uint2 xv = *(const uint2*)(xcur + swz(bl, off));
            const half_t* xh = (const half_t*)&xv;
            float v0 = tanh_fast(acc[m][0] + (float)xh[0]);
            float v1 = tanh_fast(acc[m][1] + (float)xh[1]);
            float v2 = tanh_fast(acc[m][2] + (float)xh[2]);
            float v3 = tanh_fast(acc[m][3] + (float)xh[3]);
            uint2 hv;
            hv.x = __builtin_bit_cast(u32, __builtin_amdgcn_cvt_pkrtz(v0, v1));
            hv.y = __builtin_bit_cast(u32, __builtin_amdgcn_cvt_pkrtz(v2, v3));
            *(uint2*)(hnxt + swz(bl, off)) = hv;               // next step's B-operand
            *(uint2*)(hst + m * 32) = hv;                      // global h[b][t][j]
        }
        hst += 512;
        __syncthreads();
    };

    for (int t2 = 0; t2 < 250; ++t2) {
        step(2 * t2,     hs0,        hs0 + 8192, xs0,        xs0 + 8192, false);
        step(2 * t2 + 1, hs0 + 8192, hs0,        xs0 + 8192, xs0,        2 * t2 + 1 == 499);
    }
}

// ---------------- launch ----------------
extern "C" void kernel_launch(void* const* d_in, const int* in_sizes, int n_in,
                              void* d_out, int out_size, void* d_ws, size_t ws_size,
                              hipStream_t stream) {
    const float* x    = (const float*)d_in[0];
    const float* Wih0 = (const float*)d_in[1];
    const float* Whh0 = (const float*)d_in[2];
    const float* bih0 = (const float*)d_in[3];
    const float* bhh0 = (const float*)d_in[4];
    const float* Wih1 = (const float*)d_in[5];
    const float* Whh1 = (const float*)d_in[6];
    const float* bih1 = (const float*)d_in[7];
    const float* bhh1 = (const float*)d_in[8];
    const float* fcW  = (const float*)d_in[9];
    const float* fcb  = (const float*)d_in[10];

    char* ws = (char*)d_ws;
    size_t off = 0;
    auto alloc = [&](size_t bytes) { void* p = ws + off; off += (bytes + 255) & ~(size_t)255; return p; };
    half_t* xp_buf = (half_t*)alloc((size_t)MROWS * 256 * 2);  // 65.5 MB
    half_t* h_buf  = (half_t*)alloc((size_t)MROWS * 256 * 2);  // 65.5 MB
    half_t* Wh0    = (half_t*)alloc(65536 * 2);
    half_t* Wh1    = (half_t*)alloc(65536 * 2);
    half_t* fcWh   = (half_t*)alloc(32768 * 2);
    half_t* Whh0h  = (half_t*)alloc(65536 * 2);
    half_t* Whh1h  = (half_t*)alloc(65536 * 2);
    float*  bias0  = (float*)alloc(256 * 4);
    float*  bias1  = (float*)alloc(256 * 4);
    float*  bias2  = (float*)alloc(128 * 4);

    prep_kernel<<<256, 256, 0, stream>>>(Wih0, Whh0, bih0, bhh0, Wih1, Whh1, bih1, bhh1,
                                         fcW, fcb, Wh0, Wh1, fcWh, Whh0h, Whh1h,
                                         bias0, bias1, bias2);
    // layer 0 input projection (fp32 x -> f16 xp, bias folded)
    gemm_bt<float, half_t, 256, false><<<1000, 512, 0, stream>>>(x, Wh0, bias0, xp_buf);
    // layer 0 scan
    rnn_scan_mfma<<<16, 256, 0, stream>>>(Whh0h, xp_buf, h_buf);
    // layer 1 input projection (f16 h1 -> f16 xp), reuses xp buffer
    gemm_bt<half_t, half_t, 256, false><<<1000, 512, 0, stream>>>(h_buf, Wh1, bias1, xp_buf);
    // layer 1 scan (overwrites h buffer)
    rnn_scan_mfma<<<16, 256, 0, stream>>>(Whh1h, xp_buf, h_buf);
    // FC head + sigmoid -> fp32 out
    gemm_bt<half_t, float, 128, true><<<1000, 512, 0, stream>>>(h_buf, fcWh, bias2, (float*)d_out);
}

// Round 4
// 1114.351 us; speedup vs baseline: 1.1503x; 1.1503x over previous
//
#include <hip/hip_runtime.h>
#include <hip/hip_fp16.h>

typedef _Float16 half_t;
typedef _Float16 half2_t __attribute__((ext_vector_type(2)));
typedef _Float16 f16x8 __attribute__((ext_vector_type(8)));
typedef float f32x4 __attribute__((ext_vector_type(4)));
typedef unsigned int u32;

// B=256, T=500, I=H=256, O=128, M=B*T=128000
#define MROWS 128000
#define KDIM 256

// ---------------- prep: convert weights to f16 layouts, fold biases ----------
__global__ __launch_bounds__(256) void prep_kernel(
    const float* __restrict__ Wih0, const float* __restrict__ Whh0,
    const float* __restrict__ bih0, const float* __restrict__ bhh0,
    const float* __restrict__ Wih1, const float* __restrict__ Whh1,
    const float* __restrict__ bih1, const float* __restrict__ bhh1,
    const float* __restrict__ fcW,  const float* __restrict__ fcb,
    half_t* __restrict__ Wh0, half_t* __restrict__ Wh1, half_t* __restrict__ fcWh,
    half_t* __restrict__ Whh0h, half_t* __restrict__ Whh1h,
    float* __restrict__ bias0, float* __restrict__ bias1, float* __restrict__ bias2)
{
    int e = blockIdx.x * 256 + threadIdx.x;   // 0..65535
    Wh0[e] = (half_t)Wih0[e];
    Wh1[e] = (half_t)Wih1[e];
    Whh0h[e] = (half_t)Whh0[e];
    Whh1h[e] = (half_t)Whh1[e];
    if (e < 32768) fcWh[e] = (half_t)fcW[e];
    if (e < 256) { bias0[e] = bih0[e] + bhh0[e]; bias1[e] = bih1[e] + bhh1[e]; }
    if (e < 128) { bias2[e] = fcb[e]; }
}

// ---------------- GEMM: C[M,NT] = A[M,256] * W[NT,256]^T + bias (f16 MFMA) ---
template<typename AT, typename OT, int NT, bool SIG>
__global__ __launch_bounds__(512) void gemm_bt(
    const AT* __restrict__ A, const half_t* __restrict__ W,
    const float* __restrict__ bias, OT* __restrict__ C)
{
    constexpr int K = KDIM;
    __shared__ __align__(16) half_t As[128][72];   // +8 pad: 2-way bank alias only
    __shared__ __align__(16) half_t Ws[NT][72];
    __shared__ float bs[NT];
    const int tid  = threadIdx.x;
    const int row0 = blockIdx.x * 128;
    if (tid < NT) bs[tid] = bias[tid];
    constexpr int NFRAG = NT / 64;                 // 4 (NT=256) or 2 (NT=128)
    f32x4 acc[4][NFRAG] = {};
    const int lane = tid & 63;
    const int wid  = tid >> 6;                     // 8 waves: 2 (rows) x 4 (cols)
    const int wr = wid >> 2, wc = wid & 3;

    for (int kt = 0; kt < 4; ++kt) {
        const int k0 = kt * 64;
        if constexpr (sizeof(AT) == 4) {           // fp32 A -> convert to f16
            #pragma unroll
            for (int p = 0; p < 4; ++p) {
                int idx = p * 512 + tid; int r = idx >> 4; int c4 = (idx & 15) * 4;
                const float4 v = *(const float4*)(A + (size_t)(row0 + r) * K + k0 + c4);
                half2_t h01; h01.x = (half_t)v.x; h01.y = (half_t)v.y;
                half2_t h23; h23.x = (half_t)v.z; h23.y = (half_t)v.w;
                *(half2_t*)&As[r][c4]     = h01;
                *(half2_t*)&As[r][c4 + 2] = h23;
            }
        } else {                                   // f16 A
            #pragma unroll
            for (int p = 0; p < 2; ++p) {
                int idx = p * 512 + tid; int r = idx >> 3; int c8 = (idx & 7) * 8;
                uint4 v = *(const uint4*)(A + (size_t)(row0 + r) * K + k0 + c8);
                *(uint4*)&As[r][c8] = v;
            }
        }
        #pragma unroll
        for (int p = 0; p < NT / 64; ++p) {        // stage W tile (f16)
            int idx = p * 512 + tid; int r = idx >> 3; int c8 = (idx & 7) * 8;
            uint4 v = *(const uint4*)(W + (size_t)r * K + k0 + c8);
            *(uint4*)&Ws[r][c8] = v;
        }
        __syncthreads();
        #pragma unroll
        for (int kkh = 0; kkh < 2; ++kkh) {
            const int kk = kkh * 32 + ((lane >> 4) * 8);
            f16x8 af[4], bf[NFRAG];
            #pragma unroll
            for (int m = 0; m < 4; ++m)
                af[m] = *(const f16x8*)&As[wr * 64 + m * 16 + (lane & 15)][kk];
            #pragma unroll
            for (int n = 0; n < NFRAG; ++n)
                bf[n] = *(const f16x8*)&Ws[wc * (NT / 4) + n * 16 + (lane & 15)][kk];
            #pragma unroll
            for (int m = 0; m < 4; ++m)
                #pragma unroll
                for (int n = 0; n < NFRAG; ++n)
                    acc[m][n] = __builtin_amdgcn_mfma_f32_16x16x32_f16(af[m], bf[n], acc[m][n], 0, 0, 0);
        }
        __syncthreads();
    }
    #pragma unroll
    for (int m = 0; m < 4; ++m)
        #pragma unroll
        for (int n = 0; n < NFRAG; ++n)
            #pragma unroll
            for (int jj = 0; jj < 4; ++jj) {
                int rl = wr * 64 + m * 16 + ((lane >> 4) * 4) + jj;
                int cl = wc * (NT / 4) + n * 16 + (lane & 15);
                float v = acc[m][n][jj] + bs[cl];
                if constexpr (SIG) v = 1.0f / (1.0f + __expf(-v));
                C[(size_t)(row0 + rl) * NT + cl] = (OT)v;
            }
}

// ---------------- MFMA recurrent scan ---------------------------------------
// 16 blocks x 512 threads (8 waves). Block owns 16 batch rows.
// Per step: h_new[16b][256j] = tanh(W_hh[j][k] . h[k][b] + xp[b][j])
//   - W_hh: j-eighth per wave, resident in 64 VGPRs (A-operand frags)
//   - h:    ping-pong 8KB LDS tiles [16 b][512 B], XOR-swizzled
//   - xp:   prefetch depth 2 via global_load_lds into 4 rotating 8KB slots
//   - sync: raw s_barrier with counted s_waitcnt vmcnt(3) -- stores and
//           prefetches stay in flight across barriers (never drain to 0)

typedef __attribute__((address_space(1))) const unsigned gu32;
typedef __attribute__((address_space(3))) unsigned lu32;

__device__ __forceinline__ void stage16(const void* g, void* l) {
    __builtin_amdgcn_global_load_lds((gu32*)g, (lu32*)l, 16, 0, 0);
}

__device__ __forceinline__ int swz(int b, int byteoff) {
    return b * 512 + (byteoff ^ ((b & 7) << 4));
}

__device__ __forceinline__ float tanh_fast(float x) {
    // tanh(x) = 1 - 2/(e^{2x}+1);  e^{2x} = exp2(2*log2(e)*x)
    float e = __builtin_amdgcn_exp2f(x * 2.885390082f);
    return __builtin_fmaf(-2.0f, __builtin_amdgcn_rcpf(e + 1.0f), 1.0f);
}

__global__ __launch_bounds__(512, 1) void rnn_scan_mfma(
    const half_t* __restrict__ Whh,   // [256 j][256 k] f16
    const half_t* __restrict__ xp,    // [B*T][256] f16, bias folded
    half_t* __restrict__ hout)        // [B*T][256] f16
{
    __shared__ __align__(16) char lds[16384 + 32768];
    char* const hs0 = lds;            // h: 2 x 8192 B ping-pong
    char* const xs0 = lds + 16384;    // xp: 4 x 8192 B rotating slots

    const int tid = threadIdx.x;
    const int w = tid >> 6, l = tid & 63, lq = l >> 4, bl = l & 15;
    const int blk = blockIdx.x;

    // resident W_hh frags: j = w*32 + m*16 + bl, k = kt*32 + lq*8 (+0..7)
    f16x8 wf[2][8];
    #pragma unroll
    for (int m = 0; m < 2; ++m)
        #pragma unroll
        for (int kt = 0; kt < 8; ++kt)
            wf[m][kt] = *(const f16x8*)(Whh + (size_t)(w * 32 + m * 16 + bl) * 256 + kt * 32 + lq * 8);

    // zero h slot A (h(-1) = 0)
    uint4 z = {0u, 0u, 0u, 0u};
    ((uint4*)hs0)[tid] = z;

    // per-lane xp stage source (pre-swizzled global address), at t=0
    const int b0 = tid >> 5, c0 = (tid & 31) * 16;
    const char* const srcA = (const char*)xp
        + (size_t)(blk * 16 + b0) * 500 * 512 + (c0 ^ ((b0 & 7) << 4));

    // prologue: stage xp(0) -> slot0, xp(1) -> slot1
    stage16(srcA,       xs0 + 0 * 8192 + w * 1024);
    stage16(srcA + 512, xs0 + 1 * 8192 + w * 1024);

    // h global store base: element (blk*16+bl, t, w*32 + lq*4), bytes
    char* hst = (char*)hout + ((size_t)(blk * 16 + bl) * 500 * 256 + w * 32 + lq * 4) * 2;

    __syncthreads();   // full drain once: wf loaded, zeros + slots 0,1 visible; vmcnt=0

    auto step = [&](int t, char* hcur, char* hnxt) {
        // prefetch xp(t+2) into rotating slot (clamped source keeps vmcnt uniform)
        {
            int tc = (t + 2 > 499) ? 499 : (t + 2);
            stage16(srcA + (size_t)tc * 512, xs0 + (size_t)((t + 2) & 3) * 8192 + w * 1024);
        }
        // B-operand: h[k = kt*32+lq*8 ..+7][b = bl]
        f16x8 bf[8];
        #pragma unroll
        for (int kt = 0; kt < 8; ++kt)
            bf[kt] = *(const f16x8*)(hcur + swz(bl, kt * 64 + lq * 16));
        f32x4 a0[2] = {}, a1[2] = {};      // depth-4 chains
        #pragma unroll
        for (int kt = 0; kt < 4; ++kt)
            #pragma unroll
            for (int m = 0; m < 2; ++m) {
                a0[m] = __builtin_amdgcn_mfma_f32_16x16x32_f16(wf[m][kt],     bf[kt],     a0[m], 0, 0, 0);
                a1[m] = __builtin_amdgcn_mfma_f32_16x16x32_f16(wf[m][kt + 4], bf[kt + 4], a1[m], 0, 0, 0);
            }
        const char* xcur = xs0 + (size_t)(t & 3) * 8192;
        #pragma unroll
        for (int m = 0; m < 2; ++m) {
            const int off = w * 64 + m * 32 + lq * 8;
            uint2 xv = *(const uint2*)(xcur + swz(bl, off));
            const half_t* xh = (const half_t*)&xv;
            f32x4 s = a0[m] + a1[m];
            float v0 = tanh_fast(s[0] + (float)xh[0]);
            float v1 = tanh_fast(s[1] + (float)xh[1]);
            float v2 = tanh_fast(s[2] + (float)xh[2]);
            float v3 = tanh_fast(s[3] + (float)xh[3]);
            uint2 hv;
            hv.x = __builtin_bit_cast(u32, __builtin_amdgcn_cvt_pkrtz(v0, v1));
            hv.y = __builtin_bit_cast(u32, __builtin_amdgcn_cvt_pkrtz(v2, v3));
            *(uint2*)(hnxt + swz(bl, off)) = hv;   // next step's B-operand
            *(uint2*)(hst + m * 32) = hv;          // global h[b][t][j]
        }
        hst += 512;
        // retire: stage(t+1) [2 steps old] + stores(t-1) [1 step old]; keep
        // stage(t+2) + stores(t) in flight. Then make h writes visible, barrier.
        asm volatile("s_waitcnt vmcnt(3) lgkmcnt(0)\n\ts_barrier" ::: "memory");
    };

    for (int t4 = 0; t4 < 125; ++t4) {
        const int t = t4 * 4;
        step(t,     hs0,        hs0 + 8192);
        step(t + 1, hs0 + 8192, hs0);
        step(t + 2, hs0,        hs0 + 8192);
        step(t + 3, hs0 + 8192, hs0);
    }
}

// ---------------- launch ----------------
extern "C" void kernel_launch(void* const* d_in, const int* in_sizes, int n_in,
                              void* d_out, int out_size, void* d_ws, size_t ws_size,
                              hipStream_t stream) {
    const float* x    = (const float*)d_in[0];
    const float* Wih0 = (const float*)d_in[1];
    const float* Whh0 = (const float*)d_in[2];
    const float* bih0 = (const float*)d_in[3];
    const float* bhh0 = (const float*)d_in[4];
    const float* Wih1 = (const float*)d_in[5];
    const float* Whh1 = (const float*)d_in[6];
    const float* bih1 = (const float*)d_in[7];
    const float* bhh1 = (const float*)d_in[8];
    const float* fcW  = (const float*)d_in[9];
    const float* fcb  = (const float*)d_in[10];

    char* ws = (char*)d_ws;
    size_t off = 0;
    auto alloc = [&](size_t bytes) { void* p = ws + off; off += (bytes + 255) & ~(size_t)255; return p; };
    half_t* xp_buf = (half_t*)alloc((size_t)MROWS * 256 * 2);  // 65.5 MB
    half_t* h_buf  = (half_t*)alloc((size_t)MROWS * 256 * 2);  // 65.5 MB
    half_t* Wh0    = (half_t*)alloc(65536 * 2);
    half_t* Wh1    = (half_t*)alloc(65536 * 2);
    half_t* fcWh   = (half_t*)alloc(32768 * 2);
    half_t* Whh0h  = (half_t*)alloc(65536 * 2);
    half_t* Whh1h  = (half_t*)alloc(65536 * 2);
    float*  bias0  = (float*)alloc(256 * 4);
    float*  bias1  = (float*)alloc(256 * 4);
    float*  bias2  = (float*)alloc(128 * 4);

    prep_kernel<<<256, 256, 0, stream>>>(Wih0, Whh0, bih0, bhh0, Wih1, Whh1, bih1, bhh1,
                                         fcW, fcb, Wh0, Wh1, fcWh, Whh0h, Whh1h,
                                         bias0, bias1, bias2);
    // layer 0 input projection (fp32 x -> f16 xp, bias folded)
    gemm_bt<float, half_t, 256, false><<<1000, 512, 0, stream>>>(x, Wh0, bias0, xp_buf);
    // layer 0 scan
    rnn_scan_mfma<<<16, 512, 0, stream>>>(Whh0h, xp_buf, h_buf);
    // layer 1 input projection (f16 h1 -> f16 xp), reuses xp buffer
    gemm_bt<half_t, half_t, 256, false><<<1000, 512, 0, stream>>>(h_buf, Wh1, bias1, xp_buf);
    // layer 1 scan (overwrites h buffer)
    rnn_scan_mfma<<<16, 512, 0, stream>>>(Whh1h, xp_buf, h_buf);
    // FC head + sigmoid -> fp32 out
    gemm_bt<half_t, float, 128, true><<<1000, 512, 0, stream>>>(h_buf, fcWh, bias2, (float*)d_out);
}

// Round 5
// 1112.645 us; speedup vs baseline: 1.1521x; 1.0015x over previous
//
#include <hip/hip_runtime.h>
#include <hip/hip_fp16.h>

typedef _Float16 half_t;
typedef _Float16 half2_t __attribute__((ext_vector_type(2)));
typedef _Float16 f16x8 __attribute__((ext_vector_type(8)));
typedef float f32x4 __attribute__((ext_vector_type(4)));
typedef unsigned int u32;

// B=256, T=500, I=H=256, O=128, M=B*T=128000
#define MROWS 128000
#define KDIM 256
#define TANH_SCALE 2.8853900817779268f   // 2*log2(e): folded into Whh, Wih, biases

// ---------------- prep: convert weights to f16 layouts, fold biases ----------
__global__ __launch_bounds__(256) void prep_kernel(
    const float* __restrict__ Wih0, const float* __restrict__ Whh0,
    const float* __restrict__ bih0, const float* __restrict__ bhh0,
    const float* __restrict__ Wih1, const float* __restrict__ Whh1,
    const float* __restrict__ bih1, const float* __restrict__ bhh1,
    const float* __restrict__ fcW,  const float* __restrict__ fcb,
    half_t* __restrict__ Wh0, half_t* __restrict__ Wh1, half_t* __restrict__ fcWh,
    half_t* __restrict__ Whh0h, half_t* __restrict__ Whh1h,
    float* __restrict__ bias0, float* __restrict__ bias1, float* __restrict__ bias2)
{
    const float c = TANH_SCALE;
    int e = blockIdx.x * 256 + threadIdx.x;   // 0..65535
    Wh0[e] = (half_t)(Wih0[e] * c);           // scaled: xp arrives pre-multiplied
    Wh1[e] = (half_t)(Wih1[e] * c);
    Whh0h[e] = (half_t)(Whh0[e] * c);
    Whh1h[e] = (half_t)(Whh1[e] * c);
    if (e < 32768) fcWh[e] = (half_t)fcW[e];  // FC unscaled
    if (e < 256) { bias0[e] = (bih0[e] + bhh0[e]) * c; bias1[e] = (bih1[e] + bhh1[e]) * c; }
    if (e < 128) { bias2[e] = fcb[e]; }
}

// ---------------- GEMM: C[M,NT] = A[M,256] * W[NT,256]^T + bias (f16 MFMA) ---
template<typename AT, typename OT, int NT, bool SIG>
__global__ __launch_bounds__(512) void gemm_bt(
    const AT* __restrict__ A, const half_t* __restrict__ W,
    const float* __restrict__ bias, OT* __restrict__ C)
{
    constexpr int K = KDIM;
    __shared__ __align__(16) half_t As[128][72];   // +8 pad: 2-way bank alias only
    __shared__ __align__(16) half_t Ws[NT][72];
    __shared__ float bs[NT];
    const int tid  = threadIdx.x;
    const int row0 = blockIdx.x * 128;
    if (tid < NT) bs[tid] = bias[tid];
    constexpr int NFRAG = NT / 64;                 // 4 (NT=256) or 2 (NT=128)
    f32x4 acc[4][NFRAG] = {};
    const int lane = tid & 63;
    const int wid  = tid >> 6;                     // 8 waves: 2 (rows) x 4 (cols)
    const int wr = wid >> 2, wc = wid & 3;

    for (int kt = 0; kt < 4; ++kt) {
        const int k0 = kt * 64;
        if constexpr (sizeof(AT) == 4) {           // fp32 A -> convert to f16
            #pragma unroll
            for (int p = 0; p < 4; ++p) {
                int idx = p * 512 + tid; int r = idx >> 4; int c4 = (idx & 15) * 4;
                const float4 v = *(const float4*)(A + (size_t)(row0 + r) * K + k0 + c4);
                half2_t h01; h01.x = (half_t)v.x; h01.y = (half_t)v.y;
                half2_t h23; h23.x = (half_t)v.z; h23.y = (half_t)v.w;
                *(half2_t*)&As[r][c4]     = h01;
                *(half2_t*)&As[r][c4 + 2] = h23;
            }
        } else {                                   // f16 A
            #pragma unroll
            for (int p = 0; p < 2; ++p) {
                int idx = p * 512 + tid; int r = idx >> 3; int c8 = (idx & 7) * 8;
                uint4 v = *(const uint4*)(A + (size_t)(row0 + r) * K + k0 + c8);
                *(uint4*)&As[r][c8] = v;
            }
        }
        #pragma unroll
        for (int p = 0; p < NT / 64; ++p) {        // stage W tile (f16)
            int idx = p * 512 + tid; int r = idx >> 3; int c8 = (idx & 7) * 8;
            uint4 v = *(const uint4*)(W + (size_t)r * K + k0 + c8);
            *(uint4*)&Ws[r][c8] = v;
        }
        __syncthreads();
        #pragma unroll
        for (int kkh = 0; kkh < 2; ++kkh) {
            const int kk = kkh * 32 + ((lane >> 4) * 8);
            f16x8 af[4], bf[NFRAG];
            #pragma unroll
            for (int m = 0; m < 4; ++m)
                af[m] = *(const f16x8*)&As[wr * 64 + m * 16 + (lane & 15)][kk];
            #pragma unroll
            for (int n = 0; n < NFRAG; ++n)
                bf[n] = *(const f16x8*)&Ws[wc * (NT / 4) + n * 16 + (lane & 15)][kk];
            #pragma unroll
            for (int m = 0; m < 4; ++m)
                #pragma unroll
                for (int n = 0; n < NFRAG; ++n)
                    acc[m][n] = __builtin_amdgcn_mfma_f32_16x16x32_f16(af[m], bf[n], acc[m][n], 0, 0, 0);
        }
        __syncthreads();
    }
    #pragma unroll
    for (int m = 0; m < 4; ++m)
        #pragma unroll
        for (int n = 0; n < NFRAG; ++n)
            #pragma unroll
            for (int jj = 0; jj < 4; ++jj) {
                int rl = wr * 64 + m * 16 + ((lane >> 4) * 4) + jj;
                int cl = wc * (NT / 4) + n * 16 + (lane & 15);
                float v = acc[m][n][jj] + bs[cl];
                if constexpr (SIG) v = 1.0f / (1.0f + __expf(-v));
                C[(size_t)(row0 + rl) * NT + cl] = (OT)v;
            }
}

// ---------------- MFMA recurrent scan ---------------------------------------
// 32 blocks x 256 threads (4 waves). Block owns 8 batch rows (B-frag cols
// 8..15 alias cols 0..7 -> same LDS address = broadcast; results discarded).
// Per step: h_new[8b][256j] = tanh_scaled(W_hh[j][k] . h[k][b] + xp[b][j])
//   - W_hh (pre-scaled by 2*log2e): j-quarter per wave, 128 VGPRs resident
//   - h: ping-pong 4KB LDS tiles [8 b][512 B], XOR-swizzled
//   - xp (pre-scaled): prefetch depth 3 via global_load_lds, 4 rotating slots
//   - sync: s_barrier with counted s_waitcnt vmcnt(10) -- per step per wave
//     issues 1 stage + 4 stores; keep {stage(t+3), stores(t), stores(t-1),
//     stage(t+2)} = 10 in flight, retire stage(t+1) & stores(t-2).

typedef __attribute__((address_space(1))) const unsigned gu32;
typedef __attribute__((address_space(3))) unsigned lu32;

__device__ __forceinline__ void stage16(const void* g, void* l) {
    __builtin_amdgcn_global_load_lds((gu32*)g, (lu32*)l, 16, 0, 0);
}

__device__ __forceinline__ int swz(int b, int byteoff) {
    return b * 512 + (byteoff ^ ((b & 7) << 4));
}

__device__ __forceinline__ float tanh_pre(float s) {
    // input pre-scaled by 2*log2(e): tanh = 1 - 2/(2^s + 1)
    float e = __builtin_amdgcn_exp2f(s);
    return __builtin_fmaf(-2.0f, __builtin_amdgcn_rcpf(e + 1.0f), 1.0f);
}

__global__ __launch_bounds__(256, 1) void rnn_scan_mfma(
    const half_t* __restrict__ Whh,   // [256 j][256 k] f16, pre-scaled
    const half_t* __restrict__ xp,    // [B*T][256] f16, pre-scaled + bias
    half_t* __restrict__ hout)        // [B*T][256] f16 (unscaled h)
{
    __shared__ __align__(16) char lds[8192 + 16384];
    char* const hs0 = lds;            // h: 2 x 4096 B ping-pong
    char* const xs0 = lds + 8192;     // xp: 4 x 4096 B rotating slots

    const int tid = threadIdx.x;
    const int w = tid >> 6, l = tid & 63, lq = l >> 4, bl = l & 15;
    const int b8 = bl & 7;
    const bool act = bl < 8;          // lanes owning a real batch row
    const int blk = blockIdx.x;

    // resident W_hh frags: j = w*64 + m*16 + bl, k = kt*32 + lq*8 (+0..7)
    f16x8 wf[4][8];
    #pragma unroll
    for (int m = 0; m < 4; ++m)
        #pragma unroll
        for (int kt = 0; kt < 8; ++kt)
            wf[m][kt] = *(const f16x8*)(Whh + (size_t)(w * 64 + m * 16 + bl) * 256 + kt * 32 + lq * 8);

    // zero both h tiles (h(-1) = 0)
    uint4 z = {0u, 0u, 0u, 0u};
    ((uint4*)hs0)[tid] = z;           // covers 4KB tileA with 256 threads? 256*16=4096 ✓
    ((uint4*)(hs0 + 4096))[tid] = z;

    // per-lane xp stage source (pre-swizzled global address), at t=0
    const int r0 = tid >> 5, c0 = (tid & 31) * 16;   // r0: 0..7
    const char* const srcA = (const char*)xp
        + (size_t)(blk * 8 + r0) * 500 * 512 + (c0 ^ ((r0 & 7) << 4));

    // prologue: stage xp(0..2) -> slots 0..2
    stage16(srcA,        xs0 + 0 * 4096 + w * 1024);
    stage16(srcA + 512,  xs0 + 1 * 4096 + w * 1024);
    stage16(srcA + 1024, xs0 + 2 * 4096 + w * 1024);

    // h global store base: element (blk*8+bl, t, w*64 + lq*4), bytes
    char* hst = (char*)hout + ((size_t)(blk * 8 + bl) * 500 * 256 + w * 64 + lq * 4) * 2;

    __syncthreads();   // one-time full drain: wf + zeros + slots 0..2 visible

    auto step = [&](int t, char* hcur, char* hnxt) {
        // prefetch xp(t+3) (clamped source keeps vm-op count uniform)
        {
            int tc = (t + 3 > 499) ? 499 : (t + 3);
            stage16(srcA + (size_t)tc * 512, xs0 + (size_t)((t + 3) & 3) * 4096 + w * 1024);
        }
        // B-operand: h[k = kt*32+lq*8 ..+7][b = b8] (cols 8..15 broadcast)
        f16x8 bf[8];
        #pragma unroll
        for (int kt = 0; kt < 8; ++kt)
            bf[kt] = *(const f16x8*)(hcur + swz(b8, kt * 64 + lq * 16));
        f32x4 a0[4] = {}, a1[4] = {};      // depth-4 chains per m
        #pragma unroll
        for (int kt = 0; kt < 4; ++kt)
            #pragma unroll
            for (int m = 0; m < 4; ++m) {
                a0[m] = __builtin_amdgcn_mfma_f32_16x16x32_f16(wf[m][kt],     bf[kt],     a0[m], 0, 0, 0);
                a1[m] = __builtin_amdgcn_mfma_f32_16x16x32_f16(wf[m][kt + 4], bf[kt + 4], a1[m], 0, 0, 0);
            }
        const char* xcur = xs0 + (size_t)(t & 3) * 4096;
        #pragma unroll
        for (int m = 0; m < 4; ++m) {
            const int off = w * 128 + m * 32 + lq * 8;
            uint2 xv = *(const uint2*)(xcur + swz(b8, off));
            const half_t* xh = (const half_t*)&xv;
            f32x4 s = a0[m] + a1[m];
            float v0 = tanh_pre(s[0] + (float)xh[0]);
            float v1 = tanh_pre(s[1] + (float)xh[1]);
            float v2 = tanh_pre(s[2] + (float)xh[2]);
            float v3 = tanh_pre(s[3] + (float)xh[3]);
            uint2 hv;
            hv.x = __builtin_bit_cast(u32, __builtin_amdgcn_cvt_pkrtz(v0, v1));
            hv.y = __builtin_bit_cast(u32, __builtin_amdgcn_cvt_pkrtz(v2, v3));
            if (act) {
                *(uint2*)(hnxt + swz(bl, off)) = hv;   // next step's B-operand
                *(uint2*)(hst + m * 32) = hv;          // global h[b][t][j]
            }
        }
        hst += 512;
        // keep {stage(t+3), stores(t), stores(t-1), stage(t+2)} = 10 in flight
        asm volatile("s_waitcnt vmcnt(10) lgkmcnt(0)\n\ts_barrier" ::: "memory");
    };

    for (int t2 = 0; t2 < 250; ++t2) {
        step(2 * t2,     hs0,        hs0 + 4096);
        step(2 * t2 + 1, hs0 + 4096, hs0);
    }
}

// ---------------- launch ----------------
extern "C" void kernel_launch(void* const* d_in, const int* in_sizes, int n_in,
                              void* d_out, int out_size, void* d_ws, size_t ws_size,
                              hipStream_t stream) {
    const float* x    = (const float*)d_in[0];
    const float* Wih0 = (const float*)d_in[1];
    const float* Whh0 = (const float*)d_in[2];
    const float* bih0 = (const float*)d_in[3];
    const float* bhh0 = (const float*)d_in[4];
    const float* Wih1 = (const float*)d_in[5];
    const float* Whh1 = (const float*)d_in[6];
    const float* bih1 = (const float*)d_in[7];
    const float* bhh1 = (const float*)d_in[8];
    const float* fcW  = (const float*)d_in[9];
    const float* fcb  = (const float*)d_in[10];

    char* ws = (char*)d_ws;
    size_t off = 0;
    auto alloc = [&](size_t bytes) { void* p = ws + off; off += (bytes + 255) & ~(size_t)255; return p; };
    half_t* xp_buf = (half_t*)alloc((size_t)MROWS * 256 * 2);  // 65.5 MB
    half_t* h_buf  = (half_t*)alloc((size_t)MROWS * 256 * 2);  // 65.5 MB
    half_t* Wh0    = (half_t*)alloc(65536 * 2);
    half_t* Wh1    = (half_t*)alloc(65536 * 2);
    half_t* fcWh   = (half_t*)alloc(32768 * 2);
    half_t* Whh0h  = (half_t*)alloc(65536 * 2);
    half_t* Whh1h  = (half_t*)alloc(65536 * 2);
    float*  bias0  = (float*)alloc(256 * 4);
    float*  bias1  = (float*)alloc(256 * 4);
    float*  bias2  = (float*)alloc(128 * 4);

    prep_kernel<<<256, 256, 0, stream>>>(Wih0, Whh0, bih0, bhh0, Wih1, Whh1, bih1, bhh1,
                                         fcW, fcb, Wh0, Wh1, fcWh, Whh0h, Whh1h,
                                         bias0, bias1, bias2);
    // layer 0 input projection (fp32 x -> f16 xp, bias folded, pre-scaled)
    gemm_bt<float, half_t, 256, false><<<1000, 512, 0, stream>>>(x, Wh0, bias0, xp_buf);
    // layer 0 scan
    rnn_scan_mfma<<<32, 256, 0, stream>>>(Whh0h, xp_buf, h_buf);
    // layer 1 input projection (f16 h1 -> f16 xp), reuses xp buffer
    gemm_bt<half_t, half_t, 256, false><<<1000, 512, 0, stream>>>(h_buf, Wh1, bias1, xp_buf);
    // layer 1 scan (overwrites h buffer)
    rnn_scan_mfma<<<32, 256, 0, stream>>>(Whh1h, xp_buf, h_buf);
    // FC head + sigmoid -> fp32 out
    gemm_bt<half_t, float, 128, true><<<1000, 512, 0, stream>>>(h_buf, fcWh, bias2, (float*)d_out);
}